// Round 6
// baseline (407.200 us; speedup 1.0000x reference)
//
#include <hip/hip_runtime.h>
#include <cstddef>

#define T_STEPS 256
#define OBS     32
#define ACTD    8
#define NB      4       // sequences per block
#define HPAD    80      // h row stride in f16 (160 B)
#define NSEQ    4096

typedef _Float16 f16x8 __attribute__((ext_vector_type(8)));
typedef _Float16 f16x4 __attribute__((ext_vector_type(4)));
typedef _Float16 f16x2 __attribute__((ext_vector_type(2)));
typedef float    f32x4 __attribute__((ext_vector_type(4)));

union F8 { f16x8 v; _Float16 e[8]; f16x2 h2[4]; };
union F4 { f16x4 v; _Float16 e[4]; f16x2 h2[2]; };

#define LOG2E 1.44269504088896f

// sigmoid via raw v_exp_f32 (2^x): 1/(1+2^(-x*log2e)) — 4 instr, NaN/inf-safe
__device__ __forceinline__ float fsig(float x) {
    return __builtin_amdgcn_rcpf(1.0f + __builtin_amdgcn_exp2f(x * -LOG2E));
}
// tanh(x) = 2*sigmoid(2x) - 1 — 5 instr
__device__ __forceinline__ float ftanh(float x) {
    return 2.0f * __builtin_amdgcn_rcpf(1.0f + __builtin_amdgcn_exp2f(x * (-2.0f * LOG2E))) - 1.0f;
}

__device__ __forceinline__ f16x2 pkrtz(float a, float b) {
    return __builtin_bit_cast(f16x2, __builtin_amdgcn_cvt_pkrtz(a, b));
}

template<int CTRL>
__device__ __forceinline__ float dppadd(float x) {
    int y = __builtin_amdgcn_update_dpp(0, __builtin_bit_cast(int, x), CTRL, 0xF, 0xF, true);
    return x + __builtin_bit_cast(float, y);
}
#define DPP_XOR1 0xB1   // quad_perm [1,0,3,2]
#define DPP_XOR2 0x4E   // quad_perm [2,3,0,1]
#define DPP_MIR8 0x141  // row_half_mirror
#define DPP_ROR8 0x128  // row_ror:8

__global__ __launch_bounds__(256, 4)
void lstm_fused(const float* __restrict__ obss, const float* __restrict__ actions,
                const float* __restrict__ W, const float* __restrict__ b,
                const float* __restrict__ Wdec, const float* __restrict__ bdec_p,
                float* __restrict__ out)
{
    // A rows: row 4s = seq s (s=0..3); other rows zero (register zeros).
    // h in LDS by seq row, unit-permuted (phi) for contiguous b128 frags.
    __shared__ __align__(16) _Float16 Ahi[2][NB * HPAD];
    __shared__ __align__(16) _Float16 Alo[2][NB * HPAD];
    __shared__ __align__(16) float    partb[2][NB][4];   // [buf][seq][wave]

    const int tid  = threadIdx.x;
    const int w    = tid >> 6;            // wave 0..3
    const int lane = tid & 63;
    const int g    = lane >> 4;           // k-group / seq this lane updates
    const int m    = lane & 15;           // unit-low / A-row provider
    const int u    = 16 * w + m;          // hidden unit this lane owns
    const int n0   = blockIdx.x * NB;
    const bool act = (m & 3) == 0;        // provides a real A row
    const int rho  = m >> 2;              // seq of that row
    // phi(u) = (u&3) + 4*((u>>4)&1) + 8*((u>>2)&3) + 32*(u>>5)
    const int phiu = (m & 3) + 4 * (w & 1) + 8 * (m >> 2) + 32 * (w >> 1);

    // ---- one-time: W fragments in registers (f16; h split applied to A only) ----
    f16x8 Bhh[4][2], Bxo[4];
    f16x4 Bxa[4];
    {
        const float* Wc = W + u;
#pragma unroll
        for (int e = 0; e < 4; e++) {
#pragma unroll
            for (int c = 0; c < 2; c++) {
                F8 hi;
#pragma unroll
                for (int i = 0; i < 8; i++) {
                    int k = 32 * c + 16 * (i >> 2) + 4 * g + (i & 3);  // 0..63
                    hi.e[i] = (_Float16)Wc[(40 + k) * 256 + 64 * e];
                }
                Bhh[e][c] = hi.v;
            }
            F8 xo;
#pragma unroll
            for (int i = 0; i < 8; i++) {
                int d = 16 * (i >> 2) + 4 * g + (i & 3);               // obs dim 0..31
                xo.e[i] = (_Float16)Wc[d * 256 + 64 * e];
            }
            Bxo[e] = xo.v;
            F4 xa_;
#pragma unroll
            for (int i = 0; i < 4; i++) {
                int d = 4 * g + i;                                     // act dim (k=16)
                xa_.e[i] = (d < ACTD) ? (_Float16)Wc[(OBS + d) * 256 + 64 * e]
                                      : (_Float16)0.0f;
            }
            Bxa[e] = xa_.v;
        }
    }
    const float bI = b[u], bJ = b[64 + u], bF1 = b[128 + u] + 1.0f, bO = b[192 + u];
    const float wd = Wdec[u];
    const float bd = bdec_p[0];

    for (int i = tid; i < NB * HPAD; i += 256) {
        Ahi[0][i] = (_Float16)0.0f;  Ahi[1][i] = (_Float16)0.0f;
        Alo[0][i] = (_Float16)0.0f;  Alo[1][i] = (_Float16)0.0f;
    }

    // per-lane x prefetch: active lanes only; running pointers (no per-step mul).
    // Inactive lanes keep zeros forever (loads are exec-masked) -> no selects needed.
    const float* pO = obss    + ((size_t)(n0 + rho) * T_STEPS) * OBS  + 4 * g;
    const float* pA = actions + ((size_t)(n0 + rho) * T_STEPS) * ACTD + 4 * g;
    f32x4 xo0 = {0,0,0,0}, xo1 = {0,0,0,0}, xa = {0,0,0,0};
    auto loadx = [&]() {
        if (act) {
            xo0 = *(const f32x4*)pO;
            xo1 = *(const f32x4*)(pO + 16);
            pO += OBS;
            if (g < 2) { xa = *(const f32x4*)pA; pA += ACTD; }
        }
    };
    loadx();
    float cr = 0.f;
    const f16x8 ZH8 = {0,0,0,0,0,0,0,0};

#pragma unroll 2
    for (int t = 0; t < T_STEPS; ++t) {
        const int cb  = t & 1;
        const int nb2 = cb ^ 1;
        // LDS-only barrier: x prefetch (vmcnt) may span it
        asm volatile("s_waitcnt lgkmcnt(0)\n\ts_barrier" ::: "memory");

        // h fragments first (lgkm-only dependency; issue before vmcnt-waiting cvt)
        f16x8 hh0 = ZH8, hh1 = ZH8, hl0 = ZH8, hl1 = ZH8;
        if (act) {
            const _Float16* bh = &Ahi[cb][rho * HPAD];
            const _Float16* bl = &Alo[cb][rho * HPAD];
            hh0 = *(const f16x8*)(bh + 8 * g);
            hh1 = *(const f16x8*)(bh + 32 + 8 * g);
            hl0 = *(const f16x8*)(bl + 8 * g);
            hl1 = *(const f16x8*)(bl + 32 + 8 * g);
        }

        if (t > 0 && tid < NB) {
            f32x4 pv = *(const f32x4*)&partb[nb2][tid][0];
            out[(size_t)(t - 1) * NSEQ + n0 + tid] = pv[0] + pv[1] + pv[2] + pv[3] + bd;
        }

        // current-step x frags from prefetched regs (packed cvt; zeros for inactive)
        F8 uo;
        uo.h2[0] = pkrtz(xo0[0], xo0[1]);
        uo.h2[1] = pkrtz(xo0[2], xo0[3]);
        uo.h2[2] = pkrtz(xo1[0], xo1[1]);
        uo.h2[3] = pkrtz(xo1[2], xo1[3]);
        F4 ua;
        ua.h2[0] = pkrtz(xa[0], xa[1]);
        ua.h2[1] = pkrtz(xa[2], xa[3]);
        f16x8 axo = uo.v;
        f16x4 axa = ua.v;
        if (t + 1 < T_STEPS) loadx();

        f32x4 acc[4];
#pragma unroll
        for (int e = 0; e < 4; e++) {
            f32x4 z = {0.f, 0.f, 0.f, 0.f};
            f32x4 aA = __builtin_amdgcn_mfma_f32_16x16x32_f16(axo, Bxo[e], z, 0, 0, 0);
            f32x4 aB = __builtin_amdgcn_mfma_f32_16x16x16f16(axa, Bxa[e], z, 0, 0, 0);
            aA = __builtin_amdgcn_mfma_f32_16x16x32_f16(hh0, Bhh[e][0], aA, 0, 0, 0);
            aB = __builtin_amdgcn_mfma_f32_16x16x32_f16(hh1, Bhh[e][1], aB, 0, 0, 0);
            aA = __builtin_amdgcn_mfma_f32_16x16x32_f16(hl0, Bhh[e][0], aA, 0, 0, 0);
            aB = __builtin_amdgcn_mfma_f32_16x16x32_f16(hl1, Bhh[e][1], aB, 0, 0, 0);
            acc[e] = aA + aB;
        }

        // cell update: lane owns (seq g, unit u); C row 4g -> reg 0
        {
            float gi = acc[0][0] + bI;
            float gj = acc[1][0] + bJ;
            float gf = acc[2][0] + bF1;
            float go = acc[3][0] + bO;
            float c = cr * fsig(gf) + fsig(gi) * ftanh(gj);
            cr = c;
            float h = ftanh(c) * fsig(go);
            _Float16 hhv = (_Float16)h;
            Ahi[nb2][g * HPAD + phiu] = hhv;
            Alo[nb2][g * HPAD + phiu] = (_Float16)(h - (float)hhv);
            // decode partial: reduce over the wave's 16 units (lane bits 0..3)
            float p = h * wd;
            p = dppadd<DPP_XOR1>(p);
            p = dppadd<DPP_XOR2>(p);
            p = dppadd<DPP_MIR8>(p);
            p = dppadd<DPP_ROR8>(p);
            if (m == 0) partb[cb][g][w] = p;
        }
    }

    __syncthreads();
    if (tid < NB) {
        f32x4 pv = *(const f32x4*)&partb[(T_STEPS - 1) & 1][tid][0];
        out[(size_t)(T_STEPS - 1) * NSEQ + n0 + tid] = pv[0] + pv[1] + pv[2] + pv[3] + bd;
    }
}

extern "C" void kernel_launch(void* const* d_in, const int* in_sizes, int n_in,
                              void* d_out, int out_size, void* d_ws, size_t ws_size,
                              hipStream_t stream) {
    (void)in_sizes; (void)n_in; (void)d_ws; (void)ws_size; (void)out_size;
    const float* obss    = (const float*)d_in[0];
    const float* actions = (const float*)d_in[1];
    const float* W       = (const float*)d_in[2];
    const float* b       = (const float*)d_in[3];
    const float* Wdec    = (const float*)d_in[4];
    const float* bdec    = (const float*)d_in[5];
    float* out = (float*)d_out;
    lstm_fused<<<dim3(NSEQ / NB), dim3(256), 0, stream>>>(obss, actions, W, b, Wdec, bdec, out);
}

// Round 7
// 259.273 us; speedup vs baseline: 1.5705x; 1.5705x over previous
//
#include <hip/hip_runtime.h>
#include <cstddef>

#define T_STEPS 256
#define OBS     32
#define ACTD    8
#define NB      8       // sequences per block
#define HPAD    80      // h row stride in f16 (160 B)
#define NSEQ    4096

typedef _Float16 f16x8 __attribute__((ext_vector_type(8)));
typedef _Float16 f16x4 __attribute__((ext_vector_type(4)));
typedef _Float16 f16x2 __attribute__((ext_vector_type(2)));
typedef float    f32x4 __attribute__((ext_vector_type(4)));

union F8 { f16x8 v; _Float16 e[8]; f16x2 h2[4]; };
union F4 { f16x4 v; _Float16 e[4]; f16x2 h2[2]; };

#define LOG2E 1.44269504088896f

// sigmoid via raw v_exp_f32: 1/(1+2^(-x*log2e))
__device__ __forceinline__ float fsig(float x) {
    return __builtin_amdgcn_rcpf(1.0f + __builtin_amdgcn_exp2f(x * -LOG2E));
}
// tanh(x) = 2*sigmoid(2x) - 1
__device__ __forceinline__ float ftanh(float x) {
    return 2.0f * __builtin_amdgcn_rcpf(1.0f + __builtin_amdgcn_exp2f(x * (-2.0f * LOG2E))) - 1.0f;
}

__device__ __forceinline__ f16x2 pkrtz(float a, float b) {
    return __builtin_bit_cast(f16x2, __builtin_amdgcn_cvt_pkrtz(a, b));
}

template<int CTRL>
__device__ __forceinline__ float dppadd(float x) {
    int y = __builtin_amdgcn_update_dpp(0, __builtin_bit_cast(int, x), CTRL, 0xF, 0xF, true);
    return x + __builtin_bit_cast(float, y);
}
#define DPP_XOR1 0xB1   // quad_perm [1,0,3,2]
#define DPP_XOR2 0x4E   // quad_perm [2,3,0,1]
#define DPP_MIR8 0x141  // row_half_mirror
#define DPP_ROR8 0x128  // row_ror:8

__global__ __launch_bounds__(256, 2)
void lstm_fused(const float* __restrict__ obss, const float* __restrict__ actions,
                const float* __restrict__ W, const float* __restrict__ b,
                const float* __restrict__ Wdec, const float* __restrict__ bdec_p,
                float* __restrict__ out)
{
    // A rows: row 4a+b (b<2) = seq 2a+b; rows with (r&3)>=2 are zero (reg zeros).
    // h in LDS by seq row, unit-permuted (phi) for contiguous b128 frags.
    __shared__ __align__(16) _Float16 Ahi[2][NB * HPAD];
    __shared__ __align__(16) _Float16 Alo[2][NB * HPAD];
    __shared__ __align__(16) float    partb[2][NB][4];   // [buf][seq][wave]

    const int tid  = threadIdx.x;
    const int w    = tid >> 6;            // wave 0..3
    const int lane = tid & 63;
    const int g    = lane >> 4;           // k-group / C-row-group
    const int m    = lane & 15;           // unit-low / A-row provider
    const int u    = 16 * w + m;          // hidden unit this lane owns (all 4 gates)
    const int n0   = blockIdx.x * NB;
    const bool act = (m & 3) < 2;         // provides a real A row
    const int rho  = 2 * (m >> 2) + (m & 1);   // seq index of that row
    // phi(u) = (u&3) + 4*((u>>4)&1) + 8*((u>>2)&3) + 32*(u>>5)
    const int phiu = (m & 3) + 4 * (w & 1) + 8 * (m >> 2) + 32 * (w >> 1);

    // ---- one-time: W fragments in registers (plain f16; h hi/lo is A-side) ----
    f16x8 Bhh[4][2], Bxo[4];
    f16x4 Bxa[4];
    {
        const float* Wc = W + u;
#pragma unroll
        for (int e = 0; e < 4; e++) {
#pragma unroll
            for (int c = 0; c < 2; c++) {
                F8 hi;
#pragma unroll
                for (int i = 0; i < 8; i++) {
                    int k = 32 * c + 16 * (i >> 2) + 4 * g + (i & 3);  // 0..63
                    hi.e[i] = (_Float16)Wc[(40 + k) * 256 + 64 * e];
                }
                Bhh[e][c] = hi.v;
            }
            F8 xo;
#pragma unroll
            for (int i = 0; i < 8; i++) {
                int d = 16 * (i >> 2) + 4 * g + (i & 3);               // obs dim 0..31
                xo.e[i] = (_Float16)Wc[d * 256 + 64 * e];
            }
            Bxo[e] = xo.v;
            F4 xa_;
#pragma unroll
            for (int i = 0; i < 4; i++) {
                int d = 4 * g + i;                                     // act dim (k=16)
                xa_.e[i] = (d < ACTD) ? (_Float16)Wc[(OBS + d) * 256 + 64 * e]
                                      : (_Float16)0.0f;
            }
            Bxa[e] = xa_.v;
        }
    }
    const float bI = b[u], bJ = b[64 + u], bF1 = b[128 + u] + 1.0f, bO = b[192 + u];
    const float wd = Wdec[u];
    const float bd = bdec_p[0];

    for (int i = tid; i < NB * HPAD; i += 256) {
        Ahi[0][i] = (_Float16)0.0f;  Ahi[1][i] = (_Float16)0.0f;
        Alo[0][i] = (_Float16)0.0f;  Alo[1][i] = (_Float16)0.0f;
    }

    // per-lane x prefetch: active lanes only; running pointers.
    // Inactive lanes keep zeros forever (loads exec-masked; regs init'd once).
    const float* pO = obss    + ((size_t)(n0 + rho) * T_STEPS) * OBS  + 4 * g;
    const float* pA = actions + ((size_t)(n0 + rho) * T_STEPS) * ACTD + 4 * g;
    f32x4 xo0 = {0,0,0,0}, xo1 = {0,0,0,0}, xa = {0,0,0,0};
    auto loadx = [&]() {
        if (act) {
            xo0 = *(const f32x4*)pO;
            xo1 = *(const f32x4*)(pO + 16);
            pO += OBS;
            if (g < 2) { xa = *(const f32x4*)pA; pA += ACTD; }
        }
    };
    loadx();
    float cr0 = 0.f, cr1 = 0.f;
    // h fragments: init once; only active lanes ever overwrite (stay 0 elsewhere)
    f16x8 hh0 = {0,0,0,0,0,0,0,0}, hh1 = hh0, hl0 = hh0, hl1 = hh0;

    float* pOut = out + n0 + tid;         // running output pointer (tid<NB lanes)

#pragma unroll 2
    for (int t = 0; t < T_STEPS; ++t) {
        const int cb  = t & 1;
        const int nb2 = cb ^ 1;
        // LDS-only barrier: x prefetch (vmcnt) may span it
        asm volatile("s_waitcnt lgkmcnt(0)\n\ts_barrier" ::: "memory");

        if (t > 0 && tid < NB) {
            f32x4 pv = *(const f32x4*)&partb[nb2][tid][0];
            *pOut = pv[0] + pv[1] + pv[2] + pv[3] + bd;
            pOut += NSEQ;
        }

        // current-step x frags (packed cvt; inactive lanes produce zeros)
        F8 uo;
        uo.h2[0] = pkrtz(xo0[0], xo0[1]);
        uo.h2[1] = pkrtz(xo0[2], xo0[3]);
        uo.h2[2] = pkrtz(xo1[0], xo1[1]);
        uo.h2[3] = pkrtz(xo1[2], xo1[3]);
        F4 ua;
        ua.h2[0] = pkrtz(xa[0], xa[1]);
        ua.h2[1] = pkrtz(xa[2], xa[3]);
        f16x8 axo = uo.v;
        f16x4 axa = ua.v;
        if (t + 1 < T_STEPS) loadx();

        // h fragments (active rows only; inactive keep loop-invariant zeros)
        if (act) {
            const _Float16* bh = &Ahi[cb][rho * HPAD];
            const _Float16* bl = &Alo[cb][rho * HPAD];
            hh0 = *(const f16x8*)(bh + 8 * g);
            hh1 = *(const f16x8*)(bh + 32 + 8 * g);
            hl0 = *(const f16x8*)(bl + 8 * g);
            hl1 = *(const f16x8*)(bl + 32 + 8 * g);
        }

        f32x4 acc[4];
        __builtin_amdgcn_s_setprio(1);
#pragma unroll
        for (int e = 0; e < 4; e++) {
            f32x4 z = {0.f, 0.f, 0.f, 0.f};
            f32x4 aA = __builtin_amdgcn_mfma_f32_16x16x32_f16(axo, Bxo[e], z, 0, 0, 0);
            f32x4 aB = __builtin_amdgcn_mfma_f32_16x16x16f16(axa, Bxa[e], z, 0, 0, 0);
            aA = __builtin_amdgcn_mfma_f32_16x16x32_f16(hh0, Bhh[e][0], aA, 0, 0, 0);
            aB = __builtin_amdgcn_mfma_f32_16x16x32_f16(hh1, Bhh[e][1], aB, 0, 0, 0);
            aA = __builtin_amdgcn_mfma_f32_16x16x32_f16(hl0, Bhh[e][0], aA, 0, 0, 0);
            aB = __builtin_amdgcn_mfma_f32_16x16x32_f16(hl1, Bhh[e][1], aB, 0, 0, 0);
            acc[e] = aA + aB;
        }
        __builtin_amdgcn_s_setprio(0);

        // cell update: lane owns unit u for seqs 2g+j (C rows 4g+j), j=0,1
#pragma unroll
        for (int j = 0; j < 2; j++) {
            float gi = acc[0][j] + bI;
            float gj = acc[1][j] + bJ;
            float gf = acc[2][j] + bF1;
            float go = acc[3][j] + bO;
            float& cr = j ? cr1 : cr0;
            float c = cr * fsig(gf) + fsig(gi) * ftanh(gj);
            cr = c;
            float h = ftanh(c) * fsig(go);
            _Float16 hhv = (_Float16)h;
            const int s = 2 * g + j;
            Ahi[nb2][s * HPAD + phiu] = hhv;
            Alo[nb2][s * HPAD + phiu] = (_Float16)(h - (float)hhv);
            // decode partial: reduce over the wave's 16 units (lane bits 0..3)
            float p = h * wd;
            p = dppadd<DPP_XOR1>(p);
            p = dppadd<DPP_XOR2>(p);
            p = dppadd<DPP_MIR8>(p);
            p = dppadd<DPP_ROR8>(p);
            if (m == 0) partb[cb][s][w] = p;
        }
    }

    __syncthreads();
    if (tid < NB) {
        f32x4 pv = *(const f32x4*)&partb[1][tid][0];
        *pOut = pv[0] + pv[1] + pv[2] + pv[3] + bd;
    }
}

extern "C" void kernel_launch(void* const* d_in, const int* in_sizes, int n_in,
                              void* d_out, int out_size, void* d_ws, size_t ws_size,
                              hipStream_t stream) {
    (void)in_sizes; (void)n_in; (void)d_ws; (void)ws_size; (void)out_size;
    const float* obss    = (const float*)d_in[0];
    const float* actions = (const float*)d_in[1];
    const float* W       = (const float*)d_in[2];
    const float* b       = (const float*)d_in[3];
    const float* Wdec    = (const float*)d_in[4];
    const float* bdec    = (const float*)d_in[5];
    float* out = (float*)d_out;
    lstm_fused<<<dim3(NSEQ / NB), dim3(256), 0, stream>>>(obss, actions, W, b, Wdec, bdec, out);
}